// Round 7
// baseline (607.588 us; speedup 1.0000x reference)
//
#include <hip/hip_runtime.h>
#include <math.h>

#define T_LEN 215
#define BATCH 4096
#define NFEAT 36
#define DF 215
#define KP 224               // X0 row pitch (bf16 elements), padded K
#define NROWS (BATCH*NFEAT)  // 147456
#define WP 224               // Wt row pitch in bf16 (448 B)
#define WELEMS (WP*WP)       // ushorts per W matrix (100352 B)

typedef __bf16 v8bf __attribute__((ext_vector_type(8)));
typedef float f32x16 __attribute__((ext_vector_type(16)));

static __device__ __forceinline__ float bf2f(ushort u) {
    return __uint_as_float(((uint)u) << 16);
}
static __device__ __forceinline__ ushort f2bf(float f) {
    uint x = __float_as_uint(f);
    return (ushort)((x + 0x7FFFu + ((x >> 16) & 1u)) >> 16);
}

// ---------------------------------------------------------------------------
// W prep: Wt[z][h][k] = bf16(W[k][h])  (linear, pitch WP=224, zero-padded)
// ---------------------------------------------------------------------------
__global__ __launch_bounds__(256) void wprep_kernel(
    const float* __restrict__ w1a, const float* __restrict__ w2a,
    const float* __restrict__ w1b, const float* __restrict__ w2b,
    ushort* __restrict__ wt)
{
    const float* src = (blockIdx.z == 0) ? w1a : (blockIdx.z == 1) ? w2a
                     : (blockIdx.z == 2) ? w1b : w2b;
    ushort* dst = wt + (size_t)blockIdx.z * WELEMS;
    __shared__ float tile[32][33];
    int k0 = blockIdx.x * 32, h0 = blockIdx.y * 32;
    int j = threadIdx.x & 31, i0 = threadIdx.x >> 5;
    for (int i = i0; i < 32; i += 8) {
        int k = k0 + i, h = h0 + j;
        tile[i][j] = (k < DF && h < DF) ? src[(size_t)k * DF + h] : 0.f;
    }
    __syncthreads();
    for (int i = i0; i < 32; i += 8)
        dst[(size_t)(h0 + i) * WP + k0 + j] = f2bf(tile[j][i]);
}

// ---------------------------------------------------------------------------
// BN prep: bn[z] = {bnsc[224], bnsh[224], b2s[224]} (f32, zero-padded)
// ---------------------------------------------------------------------------
__global__ void bnprep_kernel(
    const float* __restrict__ b1a, const float* __restrict__ gma,
    const float* __restrict__ bta, const float* __restrict__ mna,
    const float* __restrict__ vra, const float* __restrict__ b2a,
    const float* __restrict__ b1b, const float* __restrict__ gmb,
    const float* __restrict__ btb, const float* __restrict__ mnb,
    const float* __restrict__ vrb, const float* __restrict__ b2b,
    float* __restrict__ bn)
{
    int z = blockIdx.x, t = threadIdx.x;
    const float* B1 = z ? b1b : b1a;
    const float* Gm = z ? gmb : gma;
    const float* Bt = z ? btb : bta;
    const float* Mn = z ? mnb : mna;
    const float* Vr = z ? vrb : vra;
    const float* B2 = z ? b2b : b2a;
    float sc = 0.f, sh = 0.f, bb = 0.f;
    if (t < DF) {
        sc = Gm[t] * rsqrtf(Vr[t] + 1e-5f);
        sh = fmaf(B1[t] - Mn[t], sc, Bt[t]);
        bb = B2[t];
    }
    float* o = bn + z * 672;
    o[t] = sc; o[224 + t] = sh; o[448 + t] = bb;
}

// ---------------------------------------------------------------------------
// Encoder: 1 block per b, thread = timestep t. Scalar-path weights, pure
// v_fmac inner loop; bf16 tile staged in LDS and flushed as uint4 (coalesced).
// Block b==0 also emits S1[t] = 2*sum_n acc[n] (fused colsum).
// ---------------------------------------------------------------------------
__global__ __launch_bounds__(256) void enc_kernel(const float* __restrict__ src,
    const float* __restrict__ enc_w, const float* __restrict__ enc_b,
    ushort* __restrict__ X0, float* __restrict__ S)
{
    __shared__ float st[T_LEN * NFEAT];      // 30960 B
    __shared__ ushort sx[NFEAT * KP];        // 16128 B
    int tid = threadIdx.x;
    int b   = blockIdx.x;

    for (int i = tid; i < T_LEN * 9; i += 256) {
        int t = i / 9, q = i - t * 9;
        *(float4*)&st[t*NFEAT + q*4] =
            *(const float4*)(src + ((size_t)t*BATCH + b)*NFEAT + q*4);
    }
    __syncthreads();

    int t = tid;
    if (t < KP) {
        float acc[NFEAT];
        if (t < T_LEN) {
            float x[NFEAT];
            #pragma unroll
            for (int q = 0; q < 9; ++q)
                *(float4*)&x[q*4] = *(const float4*)&st[t*NFEAT + q*4];
            #pragma unroll
            for (int n = 0; n < NFEAT; ++n) acc[n] = enc_b[n];
            #pragma unroll 4
            for (int m = 0; m < NFEAT; ++m) {
                float xm = x[m];
                #pragma unroll
                for (int n = 0; n < NFEAT; ++n)
                    acc[n] = fmaf(xm, enc_w[m*NFEAT + n], acc[n]);
            }
            #pragma unroll
            for (int n = 0; n < NFEAT; ++n) acc[n] *= 8.0f;
        } else {
            #pragma unroll
            for (int n = 0; n < NFEAT; ++n) acc[n] = 0.f;
        }
        #pragma unroll
        for (int n = 0; n < NFEAT; ++n) sx[n*KP + t] = f2bf(acc[n]);
        if (b == 0) {                        // fused S1 (colsum of rows 0..35)
            float s = 0.f;
            #pragma unroll
            for (int n = 0; n < NFEAT; ++n) s += acc[n];
            S[t] = 2.0f * s;
        }
    }
    __syncthreads();

    uint4* dst = (uint4*)(X0 + (size_t)b * NFEAT * KP);
    const uint4* s4 = (const uint4*)sx;
    for (int i = tid; i < NFEAT*KP/8; i += 256) dst[i] = s4[i];
}

// ---------------------------------------------------------------------------
// colsum: S[t] = 2 * sum_{n<36} X[n][t]  (f32), t in [0,224)  (after gin1)
// ---------------------------------------------------------------------------
__global__ void colsum_kernel(const ushort* __restrict__ X, float* __restrict__ S)
{
    int t = threadIdx.x;
    if (t < KP) {
        float s = 0.f;
        #pragma unroll
        for (int n = 0; n < NFEAT; ++n) s += bf2f(X[n*KP + t]);
        S[t] = 2.0f * s;
    }
}

// ---------------------------------------------------------------------------
// Fused GIN layer, bf16 MFMA 32x32x16, in-place on X0. NO LDS, NO barriers:
// 1 wave per block owning a 32-row m-tile; W fragments read straight from
// global (L2-resident, identical addresses across all blocks -> broadcast).
//   Y = relu( relu(bn((X+agg) @ W1 + b1)) @ W2 + b2 )
// ---------------------------------------------------------------------------
__global__ __launch_bounds__(64) void gin_mfma_kernel(
    ushort* __restrict__ X, const float* __restrict__ S2,
    const ushort* __restrict__ Wt1, const ushort* __restrict__ Wt2,
    const float* __restrict__ bn)     // {bnsc[224], bnsh[224], b2s[224]}
{
    int lane = threadIdx.x;
    int ml   = lane & 31, half = lane >> 5;
    int row  = blockIdx.x * 32 + ml;

    // load this wave's 32 X rows as B-fragments (+ aggregation for rows<36)
    ushort* xr = X + (size_t)row * KP;
    bool agg = row < NFEAT;
    uint4 B1[14];
    #pragma unroll
    for (int kb = 0; kb < 14; ++kb) {
        uint4 r = *(const uint4*)(xr + kb*16 + half*8);
        if (agg) {
            int k0 = kb*16 + half*8;
            uint w0 = r.x, w1 = r.y, w2 = r.z, w3 = r.w;
            float a0 = bf2f((ushort)(w0 & 0xffff)) + S2[k0+0];
            float a1 = bf2f((ushort)(w0 >> 16))    + S2[k0+1];
            float a2 = bf2f((ushort)(w1 & 0xffff)) + S2[k0+2];
            float a3 = bf2f((ushort)(w1 >> 16))    + S2[k0+3];
            float a4 = bf2f((ushort)(w2 & 0xffff)) + S2[k0+4];
            float a5 = bf2f((ushort)(w2 >> 16))    + S2[k0+5];
            float a6 = bf2f((ushort)(w3 & 0xffff)) + S2[k0+6];
            float a7 = bf2f((ushort)(w3 >> 16))    + S2[k0+7];
            r.x = ((uint)f2bf(a1) << 16) | f2bf(a0);
            r.y = ((uint)f2bf(a3) << 16) | f2bf(a2);
            r.z = ((uint)f2bf(a5) << 16) | f2bf(a4);
            r.w = ((uint)f2bf(a7) << 16) | f2bf(a6);
        }
        B1[kb] = r;
    }

    uint4 B2[14];
    // ---------------- GEMM1 + BN + relu -> B2 fragments (registers) --------
    #pragma unroll
    for (int ht = 0; ht < 7; ++ht) {
        f32x16 acc;
        #pragma unroll
        for (int r = 0; r < 16; ++r) acc[r] = 0.f;
        const ushort* wbase = Wt1 + (size_t)(ht*32 + ml)*WP + half*8;
        #pragma unroll
        for (int kb = 0; kb < 14; ++kb) {
            uint4 a = *(const uint4*)(wbase + kb*16);
            acc = __builtin_amdgcn_mfma_f32_32x32x16_bf16(
                      __builtin_bit_cast(v8bf, a),
                      __builtin_bit_cast(v8bf, B1[kb]), acc, 0, 0, 0);
        }
        int hb = ht*32;
        uint d[8];
        #pragma unroll
        for (int p = 0; p < 8; ++p) {
            int r0 = 2*p;
            int h0i = hb + (r0 & 3) + 8*(r0 >> 2) + 4*half;
            float v0 = fmaxf(fmaf(acc[r0],   bn[h0i],       bn[224+h0i]),   0.f);
            float v1 = fmaxf(fmaf(acc[r0+1], bn[h0i+1],     bn[224+h0i+1]), 0.f);
            d[p] = ((uint)f2bf(v1) << 16) | f2bf(v0);
        }
        // half-swap: build B-fragments for GEMM2 (k-blocks 2ht, 2ht+1)
        uint ea = __shfl_xor(half ? d[0] : d[2], 32);
        uint eb = __shfl_xor(half ? d[1] : d[3], 32);
        uint ec = __shfl_xor(half ? d[4] : d[6], 32);
        uint ed = __shfl_xor(half ? d[5] : d[7], 32);
        B2[2*ht]   = half ? make_uint4(ea, eb, d[2], d[3])
                          : make_uint4(d[0], d[1], ea, eb);
        B2[2*ht+1] = half ? make_uint4(ec, ed, d[6], d[7])
                          : make_uint4(d[4], d[5], ec, ed);
    }

    // ---------------- GEMM2 + bias + relu -> store (bf16, in place) --------
    #pragma unroll
    for (int nt = 0; nt < 7; ++nt) {
        f32x16 acc;
        #pragma unroll
        for (int r = 0; r < 16; ++r) acc[r] = 0.f;
        const ushort* wbase = Wt2 + (size_t)(nt*32 + ml)*WP + half*8;
        #pragma unroll
        for (int kb = 0; kb < 14; ++kb) {
            uint4 a = *(const uint4*)(wbase + kb*16);
            acc = __builtin_amdgcn_mfma_f32_32x32x16_bf16(
                      __builtin_bit_cast(v8bf, a),
                      __builtin_bit_cast(v8bf, B2[kb]), acc, 0, 0, 0);
        }
        int nb = nt*32;
        #pragma unroll
        for (int g = 0; g < 4; ++g) {
            int r0 = 4*g;
            int n0 = nb + 8*g + 4*half;
            float v0 = fmaxf(acc[r0]   + bn[448+n0],   0.f);
            float v1 = fmaxf(acc[r0+1] + bn[448+n0+1], 0.f);
            float v2 = fmaxf(acc[r0+2] + bn[448+n0+2], 0.f);
            float v3 = fmaxf(acc[r0+3] + bn[448+n0+3], 0.f);
            uint lo = ((uint)f2bf(v1) << 16) | f2bf(v0);
            uint hi = ((uint)f2bf(v3) << 16) | f2bf(v2);
            if (n0 + 3 < DF) {
                *(uint2*)(xr + n0) = make_uint2(lo, hi);
            } else {
                if (n0     < DF) xr[n0]     = (ushort)(lo & 0xffff);
                if (n0 + 1 < DF) xr[n0 + 1] = (ushort)(lo >> 16);
                if (n0 + 2 < DF) xr[n0 + 2] = (ushort)(hi & 0xffff);
            }
        }
    }
}

// ---------------------------------------------------------------------------
// Final: masked mean over time (+pe, +emb) then 64->64->2 MLP
// ---------------------------------------------------------------------------
__device__ inline float wave_sum(float v) {
    #pragma unroll
    for (int off = 32; off > 0; off >>= 1) v += __shfl_down(v, off);
    return v;
}

__global__ __launch_bounds__(256) void final_kernel(const ushort* __restrict__ Y2,
    const float* __restrict__ times, const int* __restrict__ lengths,
    const float* __restrict__ stat, const float* __restrict__ emb_w,
    const float* __restrict__ emb_b, const float* __restrict__ w1,
    const float* __restrict__ b1, const float* __restrict__ w2,
    const float* __restrict__ b2, float* __restrict__ out)
{
    int b = blockIdx.x, tid = threadIdx.x;
    int lane = tid & 63, w = tid >> 6;
    int L = lengths[b];
    __shared__ float aggs[64];
    __shared__ float red[4][28];
    __shared__ float hsh[64];

    // ---- node time-sums (vectorized: 8 bf16/lane, 2 rows per wave pass) ----
    #pragma unroll
    for (int p = 0; p < 5; ++p) {
        int sub = lane >> 5, c = lane & 31;
        int n = w*9 + 2*p + sub;
        bool rowok = (2*p + sub) < 9;
        float s = 0.f;
        if (rowok && c < 28) {
            uint4 v = *(const uint4*)(Y2 + (size_t)(b*NFEAT + n)*KP + c*8);
            int t0 = c*8;
            uint arr[4] = {v.x, v.y, v.z, v.w};
            #pragma unroll
            for (int e = 0; e < 4; ++e) {
                if (t0 + 2*e     < L) s += bf2f((ushort)(arr[e] & 0xffff));
                if (t0 + 2*e + 1 < L) s += bf2f((ushort)(arr[e] >> 16));
            }
        }
        #pragma unroll
        for (int off = 16; off > 0; off >>= 1) s += __shfl_xor(s, off);
        if ((lane & 31) == 0 && rowok) aggs[28 + n] = s;
    }

    // ---- positional-encoding sums ----
    float psin[14], pcos[14];
    #pragma unroll
    for (int k = 0; k < 14; ++k) { psin[k] = 0.f; pcos[k] = 0.f; }
    if (tid < L) {
        float x = times[(size_t)tid*BATCH + b];
        #pragma unroll
        for (int k = 0; k < 14; ++k) {
            float arg = x * exp2f(-0.59601508f * (float)k);
            float s, c;
            sincosf(arg, &s, &c);
            psin[k] = s; pcos[k] = c;
        }
    }
    #pragma unroll
    for (int k = 0; k < 14; ++k) {
        float v = wave_sum(psin[k]);
        if (lane == 0) red[w][k] = v;
        v = wave_sum(pcos[k]);
        if (lane == 0) red[w][14 + k] = v;
    }
    __syncthreads();
    if (tid < 28) aggs[tid] = red[0][tid] + red[1][tid] + red[2][tid] + red[3][tid];
    __syncthreads();

    if (tid < 64) {
        float e = emb_b[tid];
        #pragma unroll
        for (int m = 0; m < 9; ++m) e = fmaf(stat[b*9 + m], emb_w[m*64 + tid], e);
        aggs[tid] = (aggs[tid] + e) / (float)(L + 1);
    }
    __syncthreads();

    if (tid < 64) {
        float a = b1[tid];
        #pragma unroll
        for (int f = 0; f < 64; ++f) a = fmaf(aggs[f], w1[f*64 + tid], a);
        hsh[tid] = fmaxf(a, 0.f);
    }
    __syncthreads();
    if (tid < 2) {
        float a = b2[tid];
        #pragma unroll
        for (int j = 0; j < 64; ++j) a = fmaf(hsh[j], w2[j*2 + tid], a);
        out[b*2 + tid] = a;
    }
}

// ---------------------------------------------------------------------------
extern "C" void kernel_launch(void* const* d_in, const int* in_sizes, int n_in,
                              void* d_out, int out_size, void* d_ws, size_t ws_size,
                              hipStream_t stream)
{
    const float* src     = (const float*)d_in[0];
    const float* stat    = (const float*)d_in[1];
    const float* times   = (const float*)d_in[2];
    const int*   lengths = (const int*)  d_in[3];
    const float* enc_w   = (const float*)d_in[5];
    const float* enc_b   = (const float*)d_in[6];
    const float* emb_w   = (const float*)d_in[7];
    const float* emb_b   = (const float*)d_in[8];
    const float* mlp_w1  = (const float*)d_in[9];
    const float* mlp_b1  = (const float*)d_in[10];
    const float* mlp_w2  = (const float*)d_in[11];
    const float* mlp_b2  = (const float*)d_in[12];
    const float* g1_w1   = (const float*)d_in[13];
    const float* g1_b1   = (const float*)d_in[14];
    const float* g1_gm   = (const float*)d_in[15];
    const float* g1_bt   = (const float*)d_in[16];
    const float* g1_mn   = (const float*)d_in[17];
    const float* g1_vr   = (const float*)d_in[18];
    const float* g1_w2   = (const float*)d_in[19];
    const float* g1_b2   = (const float*)d_in[20];
    const float* g2_w1   = (const float*)d_in[21];
    const float* g2_b1   = (const float*)d_in[22];
    const float* g2_gm   = (const float*)d_in[23];
    const float* g2_bt   = (const float*)d_in[24];
    const float* g2_mn   = (const float*)d_in[25];
    const float* g2_vr   = (const float*)d_in[26];
    const float* g2_w2   = (const float*)d_in[27];
    const float* g2_b2   = (const float*)d_in[28];

    ushort* X0 = (ushort*)d_ws;                        // 66 MB
    ushort* Wt = X0 + (size_t)NROWS * KP;              // 4 * 100352 B
    float*  S  = (float*)(Wt + 4 * (size_t)WELEMS);    // 224 f32
    float*  BN = S + 224;                              // 2 * 672 f32

    wprep_kernel<<<dim3(7, 7, 4), 256, 0, stream>>>(g1_w1, g1_w2, g2_w1, g2_w2, Wt);
    bnprep_kernel<<<2, 224, 0, stream>>>(g1_b1, g1_gm, g1_bt, g1_mn, g1_vr, g1_b2,
                                         g2_b1, g2_gm, g2_bt, g2_mn, g2_vr, g2_b2, BN);
    enc_kernel<<<BATCH, 256, 0, stream>>>(src, enc_w, enc_b, X0, S);

    gin_mfma_kernel<<<NROWS/32, 64, 0, stream>>>(X0, S, Wt, Wt + WELEMS, BN);

    colsum_kernel<<<1, 256, 0, stream>>>(X0, S);
    gin_mfma_kernel<<<NROWS/32, 64, 0, stream>>>(X0, S, Wt + 2*WELEMS, Wt + 3*WELEMS,
                                                 BN + 672);

    final_kernel<<<BATCH, 256, 0, stream>>>(X0, times, lengths, stat, emb_w, emb_b,
                                            mlp_w1, mlp_b1, mlp_w2, mlp_b2,
                                            (float*)d_out);
}